// Round 1
// baseline (290.931 us; speedup 1.0000x reference)
//
#include <hip/hip_runtime.h>
#include <math.h>

#define D 2048
#define R 128
#define NB 32
#define NS 4096
#define PSTRIDE (D + 16)   // per-chunk partial record: g[D], m, l, pad (16B-aligned stride)
#define PBASE 2304         // float offset of partial records in ws (16B aligned)
#define RSQRT_R 0.08838834764831845f   // 1/sqrt(128)
#define LN_EPS 1e-5f

// ---- k1: qq[r] = bq[r] + sum_d query[d]*Wq[d,r];  c = sum_r qq[r]*be[r] ----
__global__ void k_qq(const float* __restrict__ query, const float* __restrict__ Wq,
                     const float* __restrict__ bq, const float* __restrict__ be,
                     float* __restrict__ ws) {
    __shared__ float sred[R];
    int r = threadIdx.x;  // 128 threads
    float acc = bq[r];
    for (int d = 0; d < D; ++d) acc = fmaf(query[d], Wq[(size_t)d * R + r], acc);
    ws[D + r] = acc;            // qq
    sred[r] = acc * be[r];
    __syncthreads();
    for (int off = 64; off > 0; off >>= 1) {
        if (r < off) sred[r] += sred[r + off];
        __syncthreads();
    }
    if (r == 0) ws[D + R] = sred[0];   // c
}

// ---- k2: w[d] = sum_r We[d,r] * qq[r] ----
__global__ void k_w(const float* __restrict__ We, float* __restrict__ ws) {
    __shared__ float sqq[R];
    int tid = threadIdx.x;
    if (tid < R) sqq[tid] = ws[D + tid];
    __syncthreads();
    int d = blockIdx.x * 256 + tid;
    const float* row = We + (size_t)d * R;
    float acc = 0.f;
    #pragma unroll 8
    for (int r = 0; r < R; ++r) acc = fmaf(row[r], sqq[r], acc);
    ws[d] = acc;
}

// ---- k3: main streaming pass. One block = (b, s-chunk). 4 waves, each wave
// owns rows s0+wid, s0+wid+4, ... Online softmax per wave, LDS combine. ----
__global__ __launch_bounds__(256) void k_main(const float* __restrict__ X,
                                              const float* __restrict__ ws,
                                              float* __restrict__ partials,
                                              int cpb, int rpc) {
    const int b = blockIdx.y, chunk = blockIdx.x;
    const int tid = threadIdx.x;
    const int lane = tid & 63, wid = tid >> 6;

    // w fragment in registers: element d = lane*4 + j + k*256
    float4 w4[8];
    #pragma unroll
    for (int k = 0; k < 8; ++k)
        w4[k] = *reinterpret_cast<const float4*>(ws + lane * 4 + k * 256);
    const float c = ws[D + R];

    const int s0 = chunk * rpc;
    const int s1 = s0 + rpc;   // cpb is a power of two dividing NS -> exact

    float m = -INFINITY, l = 0.f;
    float4 acc[8];
    #pragma unroll
    for (int k = 0; k < 8; ++k) acc[k] = make_float4(0.f, 0.f, 0.f, 0.f);

    for (int s = s0 + wid; s < s1; s += 4) {
        const float* row = X + ((size_t)b * NS + s) * D;
        float4 x4[8];
        #pragma unroll
        for (int k = 0; k < 8; ++k)
            x4[k] = *reinterpret_cast<const float4*>(row + lane * 4 + k * 256);
        float dot = 0.f;
        #pragma unroll
        for (int k = 0; k < 8; ++k) {
            dot = fmaf(x4[k].x, w4[k].x, dot);
            dot = fmaf(x4[k].y, w4[k].y, dot);
            dot = fmaf(x4[k].z, w4[k].z, dot);
            dot = fmaf(x4[k].w, w4[k].w, dot);
        }
        #pragma unroll
        for (int off = 32; off > 0; off >>= 1) dot += __shfl_xor(dot, off, 64);
        const float score = (dot + c) * RSQRT_R;

        if (score > m) {               // wave-uniform branch
            const float f = __expf(m - score);
            l *= f;
            #pragma unroll
            for (int k = 0; k < 8; ++k) {
                acc[k].x *= f; acc[k].y *= f; acc[k].z *= f; acc[k].w *= f;
            }
            m = score;
        }
        const float p = __expf(score - m);
        l += p;
        #pragma unroll
        for (int k = 0; k < 8; ++k) {
            acc[k].x = fmaf(p, x4[k].x, acc[k].x);
            acc[k].y = fmaf(p, x4[k].y, acc[k].y);
            acc[k].z = fmaf(p, x4[k].z, acc[k].z);
            acc[k].w = fmaf(p, x4[k].w, acc[k].w);
        }
    }

    // ---- combine the 4 waves' partials within the block ----
    __shared__ float sm[4], sl[4];
    __shared__ __align__(16) float sacc[D];
    if (lane == 0) { sm[wid] = m; sl[wid] = l; }
    __syncthreads();
    const float mb = fmaxf(fmaxf(sm[0], sm[1]), fmaxf(sm[2], sm[3]));
    const float lb = __expf(sm[0] - mb) * sl[0] + __expf(sm[1] - mb) * sl[1] +
                     __expf(sm[2] - mb) * sl[2] + __expf(sm[3] - mb) * sl[3];
    const float coeff = __expf(m - mb);
    #pragma unroll
    for (int k = 0; k < 8; ++k) {
        acc[k].x *= coeff; acc[k].y *= coeff; acc[k].z *= coeff; acc[k].w *= coeff;
    }
    if (wid == 0) {
        #pragma unroll
        for (int k = 0; k < 8; ++k)
            *reinterpret_cast<float4*>(sacc + lane * 4 + k * 256) = acc[k];
    }
    __syncthreads();
    for (int w = 1; w < 4; ++w) {
        if (wid == w) {
            #pragma unroll
            for (int k = 0; k < 8; ++k) {
                float4* p = reinterpret_cast<float4*>(sacc + lane * 4 + k * 256);
                p->x += acc[k].x; p->y += acc[k].y; p->z += acc[k].z; p->w += acc[k].w;
            }
        }
        __syncthreads();
    }

    float* rec = partials + (size_t)(b * cpb + chunk) * PSTRIDE;
    *reinterpret_cast<float4*>(rec + tid * 4) =
        *reinterpret_cast<const float4*>(sacc + tid * 4);
    *reinterpret_cast<float4*>(rec + 1024 + tid * 4) =
        *reinterpret_cast<const float4*>(sacc + 1024 + tid * 4);
    if (tid == 0) { rec[D] = mb; rec[D + 1] = lb; }
}

// ---- k4: cross-chunk softmax merge + normalize + LayerNorm. One block per b. ----
__global__ __launch_bounds__(256) void k_fin(const float* __restrict__ partials,
                                             const float* __restrict__ gamma,
                                             const float* __restrict__ beta,
                                             float* __restrict__ out, int cpb) {
    const int b = blockIdx.x, tid = threadIdx.x;
    __shared__ float scoef[64];
    __shared__ float sred[256];
    const float* pb = partials + (size_t)b * cpb * PSTRIDE;

    // global max over chunks
    float mloc = -INFINITY;
    for (int i = tid; i < cpb; i += 256) mloc = fmaxf(mloc, pb[i * PSTRIDE + D]);
    sred[tid] = mloc; __syncthreads();
    for (int off = 128; off > 0; off >>= 1) {
        if (tid < off) sred[tid] = fmaxf(sred[tid], sred[tid + off]);
        __syncthreads();
    }
    const float mg = sred[0];
    __syncthreads();

    // coefficients and denominator
    float lloc = 0.f;
    for (int i = tid; i < cpb; i += 256) {
        const float cf = __expf(pb[i * PSTRIDE + D] - mg);
        scoef[i] = cf;
        lloc += cf * pb[i * PSTRIDE + D + 1];
    }
    sred[tid] = lloc; __syncthreads();
    for (int off = 128; off > 0; off >>= 1) {
        if (tid < off) sred[tid] += sred[tid + off];
        __syncthreads();
    }
    const float inv_l = 1.f / sred[0];
    __syncthreads();

    // g for this thread's 8 elements: d = tid*4..tid*4+3 and 1024+tid*4..
    float4 g0 = make_float4(0.f, 0.f, 0.f, 0.f), g1 = g0;
    for (int i = 0; i < cpb; ++i) {
        const float cf = scoef[i];
        const float4 a0 = *reinterpret_cast<const float4*>(pb + i * PSTRIDE + tid * 4);
        const float4 a1 = *reinterpret_cast<const float4*>(pb + i * PSTRIDE + 1024 + tid * 4);
        g0.x = fmaf(cf, a0.x, g0.x); g0.y = fmaf(cf, a0.y, g0.y);
        g0.z = fmaf(cf, a0.z, g0.z); g0.w = fmaf(cf, a0.w, g0.w);
        g1.x = fmaf(cf, a1.x, g1.x); g1.y = fmaf(cf, a1.y, g1.y);
        g1.z = fmaf(cf, a1.z, g1.z); g1.w = fmaf(cf, a1.w, g1.w);
    }
    g0.x *= inv_l; g0.y *= inv_l; g0.z *= inv_l; g0.w *= inv_l;
    g1.x *= inv_l; g1.y *= inv_l; g1.z *= inv_l; g1.w *= inv_l;

    // mean / var over D
    float s1 = g0.x + g0.y + g0.z + g0.w + g1.x + g1.y + g1.z + g1.w;
    float s2 = g0.x*g0.x + g0.y*g0.y + g0.z*g0.z + g0.w*g0.w +
               g1.x*g1.x + g1.y*g1.y + g1.z*g1.z + g1.w*g1.w;
    sred[tid] = s1; __syncthreads();
    for (int off = 128; off > 0; off >>= 1) {
        if (tid < off) sred[tid] += sred[tid + off];
        __syncthreads();
    }
    const float mean = sred[0] / (float)D;
    __syncthreads();
    sred[tid] = s2; __syncthreads();
    for (int off = 128; off > 0; off >>= 1) {
        if (tid < off) sred[tid] += sred[tid + off];
        __syncthreads();
    }
    const float var = sred[0] / (float)D - mean * mean;
    const float rstd = rsqrtf(var + LN_EPS);

    const float4 ga0 = *reinterpret_cast<const float4*>(gamma + tid * 4);
    const float4 ga1 = *reinterpret_cast<const float4*>(gamma + 1024 + tid * 4);
    const float4 be0 = *reinterpret_cast<const float4*>(beta + tid * 4);
    const float4 be1 = *reinterpret_cast<const float4*>(beta + 1024 + tid * 4);
    float4 o0, o1;
    o0.x = (g0.x - mean) * rstd * ga0.x + be0.x;
    o0.y = (g0.y - mean) * rstd * ga0.y + be0.y;
    o0.z = (g0.z - mean) * rstd * ga0.z + be0.z;
    o0.w = (g0.w - mean) * rstd * ga0.w + be0.w;
    o1.x = (g1.x - mean) * rstd * ga1.x + be1.x;
    o1.y = (g1.y - mean) * rstd * ga1.y + be1.y;
    o1.z = (g1.z - mean) * rstd * ga1.z + be1.z;
    o1.w = (g1.w - mean) * rstd * ga1.w + be1.w;
    *reinterpret_cast<float4*>(out + (size_t)b * D + tid * 4) = o0;
    *reinterpret_cast<float4*>(out + (size_t)b * D + 1024 + tid * 4) = o1;
}

extern "C" void kernel_launch(void* const* d_in, const int* in_sizes, int n_in,
                              void* d_out, int out_size, void* d_ws, size_t ws_size,
                              hipStream_t stream) {
    const float* X     = (const float*)d_in[0];
    const float* query = (const float*)d_in[1];
    const float* Wq    = (const float*)d_in[2];
    const float* bq    = (const float*)d_in[3];
    const float* We    = (const float*)d_in[4];
    const float* be    = (const float*)d_in[5];
    const float* gamma = (const float*)d_in[6];
    const float* beta  = (const float*)d_in[7];
    float* out = (float*)d_out;
    float* ws  = (float*)d_ws;

    // chunks per batch: power of two (divides NS exactly), limited by ws capacity
    size_t avail = ws_size / 4;
    int cpb = 64;
    while (cpb > 1 && (size_t)PBASE + (size_t)NB * cpb * PSTRIDE > avail) cpb >>= 1;
    const int rpc = NS / cpb;

    hipLaunchKernelGGL(k_qq, dim3(1), dim3(R), 0, stream, query, Wq, bq, be, ws);
    hipLaunchKernelGGL(k_w, dim3(D / 256), dim3(256), 0, stream, We, ws);
    hipLaunchKernelGGL(k_main, dim3(cpb, NB), dim3(256), 0, stream,
                       X, ws, ws + PBASE, cpb, rpc);
    hipLaunchKernelGGL(k_fin, dim3(NB), dim3(256), 0, stream,
                       ws + PBASE, gamma, beta, out, cpb);
}

// Round 2
// 183.620 us; speedup vs baseline: 1.5844x; 1.5844x over previous
//
#include <hip/hip_runtime.h>
#include <math.h>

#define D 2048
#define R 128
#define NB 32
#define NS 4096
#define PSTRIDE (D + 16)   // per-chunk partial record: g[D], m, l, pad (16B-aligned stride)
#define PQ 2304            // float offset of partialQ (16 x R) in ws
#define PBASE 4352         // float offset of partial records in ws (16B aligned)
#define RSQRT_R 0.08838834764831845f   // 1/sqrt(128)
#define LN_EPS 1e-5f

typedef float f4 __attribute__((ext_vector_type(4)));

// ---- k_qq1: partialQ[i][r] = sum_{d in chunk i} query[d]*Wq[d,r].  16 blocks x 128 thr ----
__global__ __launch_bounds__(128) void k_qq1(const float* __restrict__ query,
                                             const float* __restrict__ Wq,
                                             float* __restrict__ pq) {
    const int r = threadIdx.x, blk = blockIdx.x;
    const int d0 = blk * (D / 16);
    float acc = 0.f;
    #pragma unroll 8
    for (int d = 0; d < D / 16; ++d)
        acc = fmaf(query[d0 + d], Wq[(size_t)(d0 + d) * R + r], acc);
    pq[blk * R + r] = acc;
}

// ---- k_w: combine partialQ -> qq (redundant per block), c = qq.be (block 0 writes),
//          w[d] = sum_r We[d,r]*qq[r].  8 blocks x 256 thr ----
__global__ __launch_bounds__(256) void k_w(const float* __restrict__ We,
                                           const float* __restrict__ bq,
                                           const float* __restrict__ be,
                                           float* __restrict__ ws) {
    __shared__ float sqq[R], sc[R];
    const int tid = threadIdx.x;
    const float* pq = ws + PQ;
    if (tid < R) {
        float q = bq[tid];
        #pragma unroll
        for (int i = 0; i < 16; ++i) q += pq[i * R + tid];
        sqq[tid] = q;
        sc[tid] = q * be[tid];
    }
    __syncthreads();
    for (int off = 64; off > 0; off >>= 1) {
        if (tid < off) sc[tid] += sc[tid + off];
        __syncthreads();
    }
    if (blockIdx.x == 0 && tid == 0) ws[D + R] = sc[0];

    const int d = blockIdx.x * 256 + tid;
    const f4* row = reinterpret_cast<const f4*>(We + (size_t)d * R);
    float a0 = 0.f, a1 = 0.f;
    #pragma unroll
    for (int r4 = 0; r4 < R / 4; r4 += 2) {
        const f4 v0 = row[r4], v1 = row[r4 + 1];
        a0 = fmaf(v0[0], sqq[r4 * 4 + 0], a0);
        a0 = fmaf(v0[1], sqq[r4 * 4 + 1], a0);
        a0 = fmaf(v0[2], sqq[r4 * 4 + 2], a0);
        a0 = fmaf(v0[3], sqq[r4 * 4 + 3], a0);
        a1 = fmaf(v1[0], sqq[r4 * 4 + 4], a1);
        a1 = fmaf(v1[1], sqq[r4 * 4 + 5], a1);
        a1 = fmaf(v1[2], sqq[r4 * 4 + 6], a1);
        a1 = fmaf(v1[3], sqq[r4 * 4 + 7], a1);
    }
    ws[d] = a0 + a1;
}

// ---- k_main: streaming pass. One block = (b, s-chunk). 4 waves, wave owns rows
// s0+wid, +4, ... ; 2-row unroll for MLP; online softmax; parallel LDS combine. ----
__global__ __launch_bounds__(256) void k_main(const float* __restrict__ X,
                                              const float* __restrict__ ws,
                                              float* __restrict__ partials,
                                              int cpb, int rpc) {
    const int b = blockIdx.y, chunk = blockIdx.x;
    const int tid = threadIdx.x;
    const int lane = tid & 63, wid = tid >> 6;

    f4 w4[8];
    #pragma unroll
    for (int k = 0; k < 8; ++k)
        w4[k] = *reinterpret_cast<const f4*>(ws + lane * 4 + k * 256);
    const float c = ws[D + R];

    const int s0 = chunk * rpc;
    const int s1 = s0 + rpc;   // rpc % 8 == 0 for all cpb <= 512

    float m = -INFINITY, l = 0.f;
    f4 acc[8];
    #pragma unroll
    for (int k = 0; k < 8; ++k) acc[k] = (f4)(0.f);

    for (int s = s0 + wid; s < s1; s += 8) {
        const float* ra = X + ((size_t)b * NS + s) * D + lane * 4;
        const float* rb = ra + 4 * D;
        f4 xa[8], xb[8];
        #pragma unroll
        for (int k = 0; k < 8; ++k)
            xa[k] = __builtin_nontemporal_load(reinterpret_cast<const f4*>(ra + k * 256));
        #pragma unroll
        for (int k = 0; k < 8; ++k)
            xb[k] = __builtin_nontemporal_load(reinterpret_cast<const f4*>(rb + k * 256));

        float da0 = 0.f, da1 = 0.f, db0 = 0.f, db1 = 0.f;
        #pragma unroll
        for (int k = 0; k < 8; k += 2) {
            da0 = fmaf(xa[k][0], w4[k][0], da0);
            da0 = fmaf(xa[k][1], w4[k][1], da0);
            da0 = fmaf(xa[k][2], w4[k][2], da0);
            da0 = fmaf(xa[k][3], w4[k][3], da0);
            da1 = fmaf(xa[k+1][0], w4[k+1][0], da1);
            da1 = fmaf(xa[k+1][1], w4[k+1][1], da1);
            da1 = fmaf(xa[k+1][2], w4[k+1][2], da1);
            da1 = fmaf(xa[k+1][3], w4[k+1][3], da1);
            db0 = fmaf(xb[k][0], w4[k][0], db0);
            db0 = fmaf(xb[k][1], w4[k][1], db0);
            db0 = fmaf(xb[k][2], w4[k][2], db0);
            db0 = fmaf(xb[k][3], w4[k][3], db0);
            db1 = fmaf(xb[k+1][0], w4[k+1][0], db1);
            db1 = fmaf(xb[k+1][1], w4[k+1][1], db1);
            db1 = fmaf(xb[k+1][2], w4[k+1][2], db1);
            db1 = fmaf(xb[k+1][3], w4[k+1][3], db1);
        }
        float da = da0 + da1, db = db0 + db1;
        #pragma unroll
        for (int off = 32; off > 0; off >>= 1) {
            da += __shfl_xor(da, off, 64);
            db += __shfl_xor(db, off, 64);
        }
        const float sa = (da + c) * RSQRT_R;
        const float sb = (db + c) * RSQRT_R;
        const float mn = fmaxf(sa, sb);

        if (mn > m) {                 // wave-uniform
            const float f = __expf(m - mn);
            l *= f;
            #pragma unroll
            for (int k = 0; k < 8; ++k) acc[k] *= f;
            m = mn;
        }
        const float pa = __expf(sa - m);
        const float pb = __expf(sb - m);
        l += pa + pb;
        #pragma unroll
        for (int k = 0; k < 8; ++k) acc[k] += pa * xa[k] + pb * xb[k];
    }

    // ---- parallel combine of the 4 waves ----
    __shared__ float sm[4], sl[4];
    __shared__ __align__(16) float sacc[4][D];
    if (lane == 0) { sm[wid] = m; sl[wid] = l; }
    __syncthreads();
    const float mb = fmaxf(fmaxf(sm[0], sm[1]), fmaxf(sm[2], sm[3]));
    const float lb = __expf(sm[0] - mb) * sl[0] + __expf(sm[1] - mb) * sl[1] +
                     __expf(sm[2] - mb) * sl[2] + __expf(sm[3] - mb) * sl[3];
    const float coeff = __expf(m - mb);
    #pragma unroll
    for (int k = 0; k < 8; ++k)
        *reinterpret_cast<f4*>(&sacc[wid][lane * 4 + k * 256]) = acc[k] * coeff;
    __syncthreads();

    float* rec = partials + (size_t)(b * cpb + chunk) * PSTRIDE;
    {
        const int i0 = tid * 4, i1 = 1024 + tid * 4;
        f4 r0 = *reinterpret_cast<const f4*>(&sacc[0][i0]) +
                *reinterpret_cast<const f4*>(&sacc[1][i0]) +
                *reinterpret_cast<const f4*>(&sacc[2][i0]) +
                *reinterpret_cast<const f4*>(&sacc[3][i0]);
        f4 r1 = *reinterpret_cast<const f4*>(&sacc[0][i1]) +
                *reinterpret_cast<const f4*>(&sacc[1][i1]) +
                *reinterpret_cast<const f4*>(&sacc[2][i1]) +
                *reinterpret_cast<const f4*>(&sacc[3][i1]);
        *reinterpret_cast<f4*>(rec + i0) = r0;
        *reinterpret_cast<f4*>(rec + i1) = r1;
    }
    if (tid == 0) { rec[D] = mb; rec[D + 1] = lb; }
}

// ---- k_fin: cross-chunk softmax merge + normalize + LayerNorm. One block per b. ----
__global__ __launch_bounds__(512) void k_fin(const float* __restrict__ partials,
                                             const float* __restrict__ gamma,
                                             const float* __restrict__ beta,
                                             float* __restrict__ out, int cpb) {
    const int b = blockIdx.x, tid = threadIdx.x;
    __shared__ float scoef[64];
    __shared__ float sredA[512], sredB[512];
    const float* pb = partials + (size_t)b * cpb * PSTRIDE;

    float mloc = -INFINITY;
    for (int i = tid; i < cpb; i += 512) mloc = fmaxf(mloc, pb[i * PSTRIDE + D]);
    sredA[tid] = mloc; __syncthreads();
    for (int off = 256; off > 0; off >>= 1) {
        if (tid < off) sredA[tid] = fmaxf(sredA[tid], sredA[tid + off]);
        __syncthreads();
    }
    const float mg = sredA[0];
    __syncthreads();

    float lloc = 0.f;
    for (int i = tid; i < cpb; i += 512) {
        const float cf = __expf(pb[i * PSTRIDE + D] - mg);
        scoef[i] = cf;
        lloc += cf * pb[i * PSTRIDE + D + 1];
    }
    sredA[tid] = lloc; __syncthreads();
    for (int off = 256; off > 0; off >>= 1) {
        if (tid < off) sredA[tid] += sredA[tid + off];
        __syncthreads();
    }
    const float inv_l = 1.f / sredA[0];
    __syncthreads();

    // g for this thread's float4: d = tid*4..tid*4+3
    f4 g = (f4)(0.f);
    for (int i = 0; i < cpb; ++i) {
        const float cf = scoef[i];
        const f4 a = *reinterpret_cast<const f4*>(pb + (size_t)i * PSTRIDE + tid * 4);
        g[0] = fmaf(cf, a[0], g[0]);
        g[1] = fmaf(cf, a[1], g[1]);
        g[2] = fmaf(cf, a[2], g[2]);
        g[3] = fmaf(cf, a[3], g[3]);
    }
    g *= inv_l;

    const float s1 = g[0] + g[1] + g[2] + g[3];
    const float s2 = g[0]*g[0] + g[1]*g[1] + g[2]*g[2] + g[3]*g[3];
    sredA[tid] = s1; sredB[tid] = s2; __syncthreads();
    for (int off = 256; off > 0; off >>= 1) {
        if (tid < off) { sredA[tid] += sredA[tid + off]; sredB[tid] += sredB[tid + off]; }
        __syncthreads();
    }
    const float mean = sredA[0] / (float)D;
    const float var = sredB[0] / (float)D - mean * mean;
    const float rstd = rsqrtf(var + LN_EPS);

    const f4 ga = *reinterpret_cast<const f4*>(gamma + tid * 4);
    const f4 be = *reinterpret_cast<const f4*>(beta + tid * 4);
    f4 o;
    o[0] = (g[0] - mean) * rstd * ga[0] + be[0];
    o[1] = (g[1] - mean) * rstd * ga[1] + be[1];
    o[2] = (g[2] - mean) * rstd * ga[2] + be[2];
    o[3] = (g[3] - mean) * rstd * ga[3] + be[3];
    *reinterpret_cast<f4*>(out + (size_t)b * D + tid * 4) = o;
}

extern "C" void kernel_launch(void* const* d_in, const int* in_sizes, int n_in,
                              void* d_out, int out_size, void* d_ws, size_t ws_size,
                              hipStream_t stream) {
    const float* X     = (const float*)d_in[0];
    const float* query = (const float*)d_in[1];
    const float* Wq    = (const float*)d_in[2];
    const float* bq    = (const float*)d_in[3];
    const float* We    = (const float*)d_in[4];
    const float* be    = (const float*)d_in[5];
    const float* gamma = (const float*)d_in[6];
    const float* beta  = (const float*)d_in[7];
    float* out = (float*)d_out;
    float* ws  = (float*)d_ws;

    size_t avail = ws_size / 4;
    int cpb = 32;
    while (cpb > 1 && (size_t)PBASE + (size_t)NB * cpb * PSTRIDE > avail) cpb >>= 1;
    const int rpc = NS / cpb;

    hipLaunchKernelGGL(k_qq1, dim3(16), dim3(128), 0, stream, query, Wq, ws + PQ);
    hipLaunchKernelGGL(k_w, dim3(D / 256), dim3(256), 0, stream, We, bq, be, ws);
    hipLaunchKernelGGL(k_main, dim3(cpb, NB), dim3(256), 0, stream,
                       X, ws, ws + PBASE, cpb, rpc);
    hipLaunchKernelGGL(k_fin, dim3(NB), dim3(512), 0, stream,
                       ws + PBASE, gamma, beta, out, cpb);
}